// Round 8
// baseline (62.233 us; speedup 1.0000x reference)
//
#include <hip/hip_runtime.h>
#include <hip/hip_bf16.h>
#include <math.h>

using short8   = __attribute__((ext_vector_type(8))) short;
using ushort4v = __attribute__((ext_vector_type(4))) unsigned short;
using float4v  = __attribute__((ext_vector_type(4))) float;

#define D_DIM 1024
#define NCLS  40
#define WSTR  1064
#define TM    16            // rows per block
#define BATCH 32768

__device__ __forceinline__ short f2bf(float f) {
    __hip_bfloat16 h = __float2bfloat16(f);
    union { __hip_bfloat16 h; short s; } u; u.h = h;
    return u.s;
}

// ---- Kernel 1: pack W/W_rev into MFMA-fragment order (unchanged, verified):
//      Wfrag[(kk*5+t)*512 + lane*8 + e] = class(t*16+lane&15), k = kk*32+(lane>>4)*8+e
__global__ void convert_w_kernel(const float* __restrict__ W, const float* __restrict__ Wr,
                                 short* __restrict__ Wfrag) {
    int idx  = blockIdx.x * 256 + threadIdx.x;   // 0..10239
    int lane = idx & 63;
    int rest = idx >> 6;          // kk*5 + t, kk = 0..31
    int t    = rest % 5;
    int kk   = rest / 5;
    int cls  = t * 16 + (lane & 15);
    int k0   = kk * 32 + (lane >> 4) * 8;
    const float* srow = (cls < NCLS) ? (W + (size_t)cls * WSTR)
                                     : (Wr + (size_t)(cls - NCLS) * WSTR);
    short8 v;
#pragma unroll
    for (int e = 0; e < 8; ++e) v[e] = f2bf(srow[k0 + e]);
    *(short8*)(Wfrag + (size_t)idx * 8) = v;
}

// ---- Kernel 2: fused K-split GEMM (4 waves x 256-col K-quarters) + reduce + chain
__global__ __launch_bounds__(256, 4) void bichain_fused(
    const float* __restrict__ src, const short* __restrict__ Wfrag,
    const float* __restrict__ Wf, const float* __restrict__ Wr,
    const float* __restrict__ bf_, const float* __restrict__ br_,
    float* __restrict__ out)
{
    // LDS: phase1 A bufs: 4 waves x 2 bufs x [16 rows][128B] = 16KB
    //      phase2 (after barrier, overlaps): Red[4][5][64] float4 = 20KB | Lg[16][81] @20480
    __shared__ __align__(16) char smem[25664];

    const int tid  = threadIdx.x;
    const int lane = tid & 63;
    const int wave = tid >> 6;
    const int row0 = blockIdx.x * TM;
    const int i16  = lane & 15;
    const int i4   = lane >> 4;
    const int kw   = wave * 256;         // this wave's K-quarter base

    char* ldsA = smem + wave * 4096;     // 2 x 2KB private bufs
    const float* aGlob = src + (size_t)(row0 + i4) * D_DIM + kw + i16 * 4;

    float4v ap[2][4];       // A chunks (64 cols), slot = c%2
    short8  wp[2][5];       // W fragments (32 cols), slot = b%2
    float4v acc[5];
#pragma unroll
    for (int t = 0; t < 5; ++t)
#pragma unroll
        for (int r = 0; r < 4; ++r) acc[t][r] = 0.f;

// A: 16 rows x 64 cols fp32; instr j covers rows j*4+i4, 256B segments (coalesced)
#define LOADA(c) do { if ((c) < 4) {                                       \
    const float* _p = aGlob + (c) * 64;                                    \
    ap[(c)&1][0] = *(const float4v*)(_p);                                  \
    ap[(c)&1][1] = *(const float4v*)(_p + 4 * D_DIM);                      \
    ap[(c)&1][2] = *(const float4v*)(_p + 8 * D_DIM);                      \
    ap[(c)&1][3] = *(const float4v*)(_p + 12 * D_DIM); } } while (0)

// W: 5 fragments for 32-col body b (global slice kk = wave*8 + b)
#define LOADW(b) do { if ((b) < 8) {                                       \
    const short* _w = Wfrag + ((size_t)(wave * 8 + (b)) * 5 * 512) + (lane << 3); \
    wp[(b)&1][0] = *(const short8*)(_w + 0 * 512);                         \
    wp[(b)&1][1] = *(const short8*)(_w + 1 * 512);                         \
    wp[(b)&1][2] = *(const short8*)(_w + 2 * 512);                         \
    wp[(b)&1][3] = *(const short8*)(_w + 3 * 512);                         \
    wp[(b)&1][4] = *(const short8*)(_w + 4 * 512); } } while (0)

// cvt + swizzled ds_write_b64 (verified R6 path): slot' = i16 ^ ((row&7)<<1)
#define DSW1(c, j) {                                                       \
    int _r = (j) * 4 + i4;                                                 \
    ushort4v _v;                                                           \
    _v[0] = (unsigned short)f2bf(ap[(c)&1][j][0]);                         \
    _v[1] = (unsigned short)f2bf(ap[(c)&1][j][1]);                         \
    _v[2] = (unsigned short)f2bf(ap[(c)&1][j][2]);                         \
    _v[3] = (unsigned short)f2bf(ap[(c)&1][j][3]);                         \
    *(ushort4v*)(_b + _r * 128 + ((i16 ^ ((_r & 7) << 1)) << 3)) = _v; }
#define DSW(c) do { if ((c) < 4) {                                         \
    char* _b = ldsA + ((c)&1) * 2048;                                      \
    DSW1(c, 0) DSW1(c, 1) DSW1(c, 2) DSW1(c, 3) } } while (0)

// body b consumes 32-col half ks=b&1 of chunk c=b>>1 (verified R6 fragment read)
#define MFMA_(b) do {                                                      \
    const char* _fb = ldsA + (((b) >> 1) & 1) * 2048 + i16 * 128;          \
    const int _sw = (i16 & 7) << 1;                                        \
    short8 _a = *(const short8*)(_fb + (((((b)&1) * 8 + i4 * 2)) ^ _sw) * 8); \
    acc[0] = __builtin_amdgcn_mfma_f32_16x16x32_bf16(_a, wp[(b)&1][0], acc[0], 0, 0, 0); \
    acc[1] = __builtin_amdgcn_mfma_f32_16x16x32_bf16(_a, wp[(b)&1][1], acc[1], 0, 0, 0); \
    acc[2] = __builtin_amdgcn_mfma_f32_16x16x32_bf16(_a, wp[(b)&1][2], acc[2], 0, 0, 0); \
    acc[3] = __builtin_amdgcn_mfma_f32_16x16x32_bf16(_a, wp[(b)&1][3], acc[3], 0, 0, 0); \
    acc[4] = __builtin_amdgcn_mfma_f32_16x16x32_bf16(_a, wp[(b)&1][4], acc[4], 0, 0, 0); \
  } while (0)

    // prologue: 2 A chunks + first W in flight, chunk 0 staged
    LOADA(0); LOADA(1); LOADW(0); DSW(0);
    // 8 bodies (4 chunks x 2 halves); even body: prefetch A; odd body: stage next chunk
    LOADW(1); LOADA(2); MFMA_(0);
    LOADW(2); DSW(1);   MFMA_(1);
    LOADW(3); LOADA(3); MFMA_(2);
    LOADW(4); DSW(2);   MFMA_(3);
    LOADW(5);           MFMA_(4);
    LOADW(6); DSW(3);   MFMA_(5);
    LOADW(7);           MFMA_(6);
                        MFMA_(7);

#undef LOADA
#undef LOADW
#undef DSW1
#undef DSW
#undef MFMA_

    __syncthreads();   // all waves done with A bufs; smem reused for reduction

    // ---- partial-accumulator reduce across the 4 K-quarter waves
    float4v* Red = (float4v*)smem;               // [wave][t][lane] float4 = 20KB
#pragma unroll
    for (int t = 0; t < 5; ++t)
        Red[(wave * 5 + t) * 64 + lane] = acc[t];
    __syncthreads();

    float* Lg = (float*)(smem + 20480);          // [16][81]
    for (int item = tid; item < 320; item += 256) {
        int t = item >> 6, l = item & 63;
        float4v v = Red[t * 64 + l];
#pragma unroll
        for (int w = 1; w < 4; ++w) {
            float4v u = Red[(w * 5 + t) * 64 + l];
#pragma unroll
            for (int r = 0; r < 4; ++r) v[r] += u[r];
        }
        int cls = t * 16 + (l & 15);
        int rw  = (l >> 4) * 4;                  // C/D layout: row=(lane>>4)*4+reg
#pragma unroll
        for (int r = 0; r < 4; ++r) Lg[(rw + r) * 81 + cls] = v[r];
    }
    __syncthreads();

    // ---- sequential chain: one thread per (row, dir); scores overwrite logits in LDS
    if (tid < 32) {
        const int row = tid >> 1;
        const int dir = tid & 1;
        const float* Wt = dir ? Wr : Wf;
        const float* bi = dir ? br_ : bf_;
        float s[NCLS];
#pragma unroll
        for (int i = 0; i < NCLS; ++i) {
            float z = Lg[row * 81 + dir * NCLS + i] + bi[i];
#pragma unroll
            for (int j = 0; j < i; ++j)
                z += s[j] * Wt[i * WSTR + D_DIM + j];
            s[i] = 1.f / (1.f + __expf(-z));
            Lg[row * 81 + dir * NCLS + i] = s[i];
        }
    }
    __syncthreads();

    // ---- combine + coalesced write: out[:,c] = 0.5*(fwd[c] + rev[39-c])
    float* outp = out + (size_t)row0 * NCLS;
    for (int idx = tid; idx < TM * NCLS; idx += 256) {
        int row = idx / NCLS, c = idx - row * NCLS;
        outp[idx] = 0.5f * (Lg[row * 81 + c] + Lg[row * 81 + NCLS + (NCLS - 1 - c)]);
    }
}

extern "C" void kernel_launch(void* const* d_in, const int* in_sizes, int n_in,
                              void* d_out, int out_size, void* d_ws, size_t ws_size,
                              hipStream_t stream) {
    const float* src = (const float*)d_in[0];
    // d_in[1] = attn_mask, unused by the reference
    const float* W   = (const float*)d_in[2];
    const float* b   = (const float*)d_in[3];
    const float* Wr  = (const float*)d_in[4];
    const float* br  = (const float*)d_in[5];
    float* out = (float*)d_out;
    short* Wfrag = (short*)d_ws;   // 160KB fragment-ordered bf16 weights

    convert_w_kernel<<<40, 256, 0, stream>>>(W, Wr, Wfrag);
    bichain_fused<<<BATCH / TM, 256, 0, stream>>>(src, Wfrag, W, Wr, b, br, out);
}

// Round 9
// 44.586 us; speedup vs baseline: 1.3958x; 1.3958x over previous
//
#include <hip/hip_runtime.h>
#include <hip/hip_bf16.h>
#include <math.h>

using short8   = __attribute__((ext_vector_type(8))) short;
using ushort4v = __attribute__((ext_vector_type(4))) unsigned short;
using float4v  = __attribute__((ext_vector_type(4))) float;

#define D_DIM 1024
#define NCLS  40
#define WSTR  1064
#define TM    64
#define NCH   16            // 1024 / 64 K-chunks

__device__ __forceinline__ short f2bf(float f) {
    __hip_bfloat16 h = __float2bfloat16(f);
    union { __hip_bfloat16 h; short s; } u; u.h = h;
    return u.s;
}

// ---- Kernel 1: pack W/W_rev into MFMA-fragment order (unchanged, verified):
//      Wfrag[((ch*2+ks)*5+t)*512 + lane*8 + e] = class(t*16+lane&15), k=ch*64+ks*32+(lane>>4)*8+e
__global__ void convert_w_kernel(const float* __restrict__ W, const float* __restrict__ Wr,
                                 short* __restrict__ Wfrag) {
    int idx  = blockIdx.x * 256 + threadIdx.x;
    int lane = idx & 63;
    int rest = idx >> 6;
    int t    = rest % 5;
    int rest2 = rest / 5;
    int ks   = rest2 & 1;
    int ch   = rest2 >> 1;
    int cls  = t * 16 + (lane & 15);
    int k0   = ch * 64 + ks * 32 + (lane >> 4) * 8;
    const float* srow = (cls < NCLS) ? (W + (size_t)cls * WSTR)
                                     : (Wr + (size_t)(cls - NCLS) * WSTR);
    short8 v;
#pragma unroll
    for (int e = 0; e < 8; ++e) v[e] = f2bf(srow[k0 + e]);
    *(short8*)(Wfrag + (size_t)idx * 8) = v;
}

// ---- Kernel 2: R6 structure + per-block/wave K-phase rotation (channel de-camping)
__global__ __launch_bounds__(256, 2) void bichain_main(
    const float* __restrict__ src, const short* __restrict__ Wfrag,
    const float* __restrict__ Wf, const float* __restrict__ Wr,
    const float* __restrict__ bf_, const float* __restrict__ br_,
    float* __restrict__ out)
{
    // LDS: per-wave-private bf16 A tiles: 4 waves x 3 bufs x [16 rows][128B] = 24KB
    // epilogue reuses as Lg[64][81] fp32 (20.7KB)
    __shared__ __align__(16) char smem[24576];

    const int tid  = threadIdx.x;
    const int lane = tid & 63;
    const int wave = tid >> 6;
    const int row0 = blockIdx.x * TM;
    const int i16  = lane & 15;
    const int i4   = lane >> 4;

    // K-phase rotation: de-lockstep the grid's chunk walk so instantaneous addresses
    // cover all 256B-interleave residues (channel de-camping). Bijective over 16.
    const int phase = ((blockIdx.x & 15) * 11 + wave * 4) & 15;
#define CID(i) (((i) + phase) & 15)

    char* ldsW = smem + wave * 6144;           // this wave's 3 buffers
    const float* aGlob = src + (size_t)(row0 + wave * 16 + i4) * D_DIM + i16 * 4;

    float4v ap[3][4];      // pending A chunks (slot = loop-index%3, static idx)
    short8  wp[2][10];     // pending W fragments (slot = loop-index%2)
    float4v acc[5];
#pragma unroll
    for (int t = 0; t < 5; ++t)
#pragma unroll
        for (int r = 0; r < 4; ++r) acc[t][r] = 0.f;

#define LOADA(i) do { if ((i) < NCH) {                                     \
    const float* _p = aGlob + CID(i) * 64;                                 \
    ap[(i)%3][0] = *(const float4v*)(_p);                                  \
    ap[(i)%3][1] = *(const float4v*)(_p + 4 * D_DIM);                      \
    ap[(i)%3][2] = *(const float4v*)(_p + 8 * D_DIM);                      \
    ap[(i)%3][3] = *(const float4v*)(_p + 12 * D_DIM); } } while (0)

#define LOADW(i) do { if ((i) < NCH) {                                     \
    const short* _w = Wfrag + (size_t)CID(i) * 5120 + (lane << 3);         \
    wp[(i)%2][0] = *(const short8*)(_w + 0 * 512);                         \
    wp[(i)%2][1] = *(const short8*)(_w + 1 * 512);                         \
    wp[(i)%2][2] = *(const short8*)(_w + 2 * 512);                         \
    wp[(i)%2][3] = *(const short8*)(_w + 3 * 512);                         \
    wp[(i)%2][4] = *(const short8*)(_w + 4 * 512);                         \
    wp[(i)%2][5] = *(const short8*)(_w + 5 * 512);                         \
    wp[(i)%2][6] = *(const short8*)(_w + 6 * 512);                         \
    wp[(i)%2][7] = *(const short8*)(_w + 7 * 512);                         \
    wp[(i)%2][8] = *(const short8*)(_w + 8 * 512);                         \
    wp[(i)%2][9] = *(const short8*)(_w + 9 * 512); } } while (0)

// cvt fp32->bf16 + swizzled ds_write_b64 (verified): slot' = i16 ^ ((row&7)<<1)
#define DSW1(i, j) {                                                       \
    int _r = (j) * 4 + i4;                                                 \
    ushort4v _v;                                                           \
    _v[0] = (unsigned short)f2bf(ap[(i)%3][j][0]);                         \
    _v[1] = (unsigned short)f2bf(ap[(i)%3][j][1]);                         \
    _v[2] = (unsigned short)f2bf(ap[(i)%3][j][2]);                         \
    _v[3] = (unsigned short)f2bf(ap[(i)%3][j][3]);                         \
    *(ushort4v*)(_b + _r * 128 + ((i16 ^ ((_r & 7) << 1)) << 3)) = _v; }
#define DSW(i) do { if ((i) < NCH) {                                       \
    char* _b = ldsW + ((i)%3) * 2048;                                      \
    DSW1(i, 0) DSW1(i, 1) DSW1(i, 2) DSW1(i, 3) } } while (0)

// fragment reads (swizzled, conflict-free b128) + 10 MFMA; chunk pairing consistent:
// LDS slot i%3 holds A of CID(i), wp[i%2] holds W of CID(i)
#define MFMA_(i) do {                                                      \
    const char* _fb = ldsW + ((i)%3) * 2048 + i16 * 128;                   \
    const int _sw = (i16 & 7) << 1;                                        \
    short8 _a0 = *(const short8*)(_fb + (((i4 * 2)     ^ _sw) << 3));      \
    acc[0] = __builtin_amdgcn_mfma_f32_16x16x32_bf16(_a0, wp[(i)%2][0], acc[0], 0, 0, 0); \
    acc[1] = __builtin_amdgcn_mfma_f32_16x16x32_bf16(_a0, wp[(i)%2][1], acc[1], 0, 0, 0); \
    acc[2] = __builtin_amdgcn_mfma_f32_16x16x32_bf16(_a0, wp[(i)%2][2], acc[2], 0, 0, 0); \
    acc[3] = __builtin_amdgcn_mfma_f32_16x16x32_bf16(_a0, wp[(i)%2][3], acc[3], 0, 0, 0); \
    acc[4] = __builtin_amdgcn_mfma_f32_16x16x32_bf16(_a0, wp[(i)%2][4], acc[4], 0, 0, 0); \
    short8 _a1 = *(const short8*)(_fb + (((8 + i4 * 2) ^ _sw) << 3));      \
    acc[0] = __builtin_amdgcn_mfma_f32_16x16x32_bf16(_a1, wp[(i)%2][5], acc[0], 0, 0, 0); \
    acc[1] = __builtin_amdgcn_mfma_f32_16x16x32_bf16(_a1, wp[(i)%2][6], acc[1], 0, 0, 0); \
    acc[2] = __builtin_amdgcn_mfma_f32_16x16x32_bf16(_a1, wp[(i)%2][7], acc[2], 0, 0, 0); \
    acc[3] = __builtin_amdgcn_mfma_f32_16x16x32_bf16(_a1, wp[(i)%2][8], acc[3], 0, 0, 0); \
    acc[4] = __builtin_amdgcn_mfma_f32_16x16x32_bf16(_a1, wp[(i)%2][9], acc[4], 0, 0, 0); \
  } while (0)

#define BODY(i) do { LOADW((i)+1); LOADA((i)+3); DSW((i)+1); MFMA_(i); } while (0)

    LOADA(0); LOADA(1); LOADA(2); LOADW(0); DSW(0);
    BODY(0);  BODY(1);  BODY(2);  BODY(3);
    BODY(4);  BODY(5);  BODY(6);  BODY(7);
    BODY(8);  BODY(9);  BODY(10); BODY(11);
    BODY(12); BODY(13); BODY(14); BODY(15);

#undef LOADA
#undef LOADW
#undef DSW1
#undef DSW
#undef MFMA_
#undef BODY
#undef CID

    __syncthreads();   // all waves done with private LDS before reuse

    // ---- logits -> LDS  (C/D layout: col = lane&15, row = (lane>>4)*4 + reg)
    float* Lg = (float*)smem;   // [64][81]
#pragma unroll
    for (int t = 0; t < 5; ++t)
#pragma unroll
        for (int r = 0; r < 4; ++r) {
            int row = wave * 16 + i4 * 4 + r;
            int cls = t * 16 + i16;
            Lg[row * 81 + cls] = acc[t][r];
        }
    __syncthreads();

    // ---- sequential chain, fp32, one thread per (row, direction); scores in-place
    if (tid < 128) {
        const int row = tid >> 1;
        const int dir = tid & 1;
        const float* Wt = dir ? Wr : Wf;
        const float* bi = dir ? br_ : bf_;
        float s[NCLS];
#pragma unroll
        for (int i = 0; i < NCLS; ++i) {
            float z = Lg[row * 81 + dir * NCLS + i] + bi[i];
#pragma unroll
            for (int j = 0; j < i; ++j)
                z += s[j] * Wt[i * WSTR + D_DIM + j];
            s[i] = 1.f / (1.f + __expf(-z));
            Lg[row * 81 + dir * NCLS + i] = s[i];
        }
    }
    __syncthreads();

    // ---- combine + coalesced write: out[:,c] = 0.5*(fwd[c] + rev[39-c])
    float* outp = out + (size_t)row0 * NCLS;
    for (int idx = tid; idx < TM * NCLS; idx += 256) {
        int row = idx / NCLS;
        int c   = idx - row * NCLS;
        outp[idx] = 0.5f * (Lg[row * 81 + c] + Lg[row * 81 + NCLS + (NCLS - 1 - c)]);
    }
}

extern "C" void kernel_launch(void* const* d_in, const int* in_sizes, int n_in,
                              void* d_out, int out_size, void* d_ws, size_t ws_size,
                              hipStream_t stream) {
    const float* src = (const float*)d_in[0];
    // d_in[1] = attn_mask, unused by the reference
    const float* W   = (const float*)d_in[2];
    const float* b   = (const float*)d_in[3];
    const float* Wr  = (const float*)d_in[4];
    const float* br  = (const float*)d_in[5];
    float* out = (float*)d_out;
    short* Wfrag = (short*)d_ws;   // 160KB fragment-ordered bf16 weights

    convert_w_kernel<<<40, 256, 0, stream>>>(W, Wr, Wfrag);
    bichain_main<<<512, 256, 0, stream>>>(src, Wfrag, W, Wr, b, br, out);
}